// Round 1
// baseline (1973.454 us; speedup 1.0000x reference)
//
#include <hip/hip_runtime.h>

// MUL=128, Z=10, L_DIMS=(1,3,5,7) offs (0,1,4,9), MM_DIMS=(1,3)

__device__ __forceinline__ float silu_f(float x) {
  return x / (1.0f + __expf(-x));
}

__global__ void k_zero_int(int* p, int n) {
  int i = blockIdx.x * blockDim.x + threadIdx.x;
  if (i < n) p[i] = 0;
}

// Mc = M1@M2@M3@M4 / 2048  (linear MLP collapse), Mc is [16,256]
__global__ __launch_bounds__(256) void k_prep(
    const float* __restrict__ M1, const float* __restrict__ M2,
    const float* __restrict__ M3, const float* __restrict__ M4,
    float* __restrict__ Mc) {
  __shared__ float T1[16 * 64];
  __shared__ float T2[16 * 64];
  int t = threadIdx.x;
  for (int i = t; i < 16 * 64; i += 256) {
    int r = i >> 6, c = i & 63;
    float s = 0.f;
    for (int k = 0; k < 64; k++) s += M1[r * 64 + k] * M2[k * 64 + c];
    T1[i] = s;
  }
  __syncthreads();
  for (int i = t; i < 16 * 64; i += 256) {
    int r = i >> 6, c = i & 63;
    float s = 0.f;
    for (int k = 0; k < 64; k++) s += T1[r * 64 + k] * M3[k * 64 + c];
    T2[i] = s;
  }
  __syncthreads();
  for (int i = t; i < 16 * 256; i += 256) {
    int r = i >> 8, c = i & 255;
    float s = 0.f;
    for (int k = 0; k < 64; k++) s += T2[r * 64 + k] * M4[k * 256 + c];
    Mc[i] = s * (1.0f / 2048.0f);
  }
}

// x = node_feats @ W_up / sqrt(128)   one block per node, 128 threads
__global__ __launch_bounds__(128) void k_up(const float* __restrict__ nf,
                                            const float* __restrict__ W,
                                            float* __restrict__ x, int Nn) {
  int n = blockIdx.x;
  int v = threadIdx.x;
  __shared__ float row[128];
  row[v] = nf[n * 128 + v];
  __syncthreads();
  float s = 0.f;
#pragma unroll 8
  for (int k = 0; k < 128; k++) s += row[k] * W[k * 128 + v];
  x[n * 128 + v] = s * 0.08838834764831845f;
}

__global__ void k_count(const int* __restrict__ recv, int* __restrict__ deg, int E) {
  int e = blockIdx.x * blockDim.x + threadIdx.x;
  if (e < E) atomicAdd(&deg[recv[e]], 1);
}

// exclusive scan of deg -> rowstart[0..N], cursor copy. single block 1024 threads.
__global__ __launch_bounds__(1024) void k_scan(const int* __restrict__ deg,
                                               int* __restrict__ rowstart,
                                               int* __restrict__ cursor, int Nn) {
  __shared__ int part[1024];
  int t = threadIdx.x;
  int chunk = (Nn + 1023) / 1024;
  int lo = t * chunk;
  int hi = lo + chunk; if (hi > Nn) hi = Nn; if (lo > Nn) lo = Nn;
  int s = 0;
  for (int i = lo; i < hi; i++) s += deg[i];
  part[t] = s;
  __syncthreads();
  for (int o = 1; o < 1024; o <<= 1) {
    int v = (t >= o) ? part[t - o] : 0;
    __syncthreads();
    part[t] += v;
    __syncthreads();
  }
  int base = (t == 0) ? 0 : part[t - 1];
  for (int i = lo; i < hi; i++) {
    rowstart[i] = base;
    cursor[i] = base;
    base += deg[i];
  }
  if (t == 1023) rowstart[Nn] = part[1023];
}

__global__ void k_fill(const int* __restrict__ recv, int* __restrict__ cursor,
                       int* __restrict__ elist, int E) {
  int e = blockIdx.x * blockDim.x + threadIdx.x;
  if (e < E) {
    int p = atomicAdd(&cursor[recv[e]], 1);
    elist[p] = e;
  }
}

// ---------------- main fused per-node kernel ----------------
// One block per receiver node. Processes its incident edges 8 at a time:
// radial MLPs in LDS, channelwise TP chain, register accumulation of
// msg[128,16] / mm[128,4] / density, then fused per_l_linear epilogue.
__global__ __launch_bounds__(256) void k_gather(
    const float* __restrict__ x, const float* __restrict__ edge_attrs,
    const float* __restrict__ edge_feats, const float* __restrict__ mminv,
    const float* __restrict__ mmattrs, const int* __restrict__ sender,
    const float* __restrict__ W1, const float* __restrict__ W2,
    const float* __restrict__ W3, const float* __restrict__ W4,
    const float* __restrict__ Mc, const float* __restrict__ Wd,
    const float* __restrict__ Wlin, const float* __restrict__ Wmlin,
    const int* __restrict__ rowstart, const int* __restrict__ elist,
    float* __restrict__ linm, float* __restrict__ linmm, int Nn) {
  const int n = blockIdx.x;
  const int t = threadIdx.x;
  const int start = rowstart[n], end = rowstart[n + 1];

  __shared__ float ef[8][16];
  __shared__ float hA[8][64];
  __shared__ float hB[8][64];
  __shared__ float w4s[8][512];   // transposed: [l*128+u]
  __shared__ float wmms[8][256];  // transposed: [j*128+u]
  __shared__ float xjs[8][128];
  __shared__ float shs[8][16];
  __shared__ float mmshs[8][4];
  __shared__ float denss[8];
  __shared__ int eS[8], sS[8];
  __shared__ float dsum_s;
  __shared__ float msg_s[128][17];  // +1 pad
  __shared__ float mm_s[128][5];

  float accm[8] = {0, 0, 0, 0, 0, 0, 0, 0};
  float accmm0 = 0.f, accmm1 = 0.f;
  float accd = 0.f;

  const int u = t & 127;
  const int half = t >> 7;  // wave-uniform
  const int gwave = t >> 6;
  const int o6 = t & 63;

  for (int base = start; base < end; base += 8) {
    __syncthreads();
    if (t < 8) {
      int g = t;
      if (base + g < end) {
        int e = elist[base + g];
        eS[g] = e;
        sS[g] = sender[e];
      } else {
        eS[g] = -1;
        sS[g] = 0;
        denss[g] = 0.f;
      }
    }
    __syncthreads();
    if (t < 128) {
      int g = t >> 4, j = t & 15;
      int e = eS[g];
      float v = 0.f, sh = 0.f;
      if (e >= 0) {
        int s = sS[g];
        v = (j < 8) ? edge_feats[e * 8 + j] : mminv[s * 8 + (j - 8)];
        sh = edge_attrs[e * 16 + j];
      }
      ef[g][j] = v;
      shs[g][j] = sh;
    } else if (t < 160) {
      int g = (t - 128) >> 2, j = (t - 128) & 3;
      mmshs[g][j] = (eS[g] >= 0) ? mmattrs[sS[g] * 4 + j] : 0.f;
    }
    for (int i = t; i < 1024; i += 256) {
      int g = i >> 7, uu = i & 127;
      xjs[g][uu] = (eS[g] >= 0) ? x[sS[g] * 128 + uu] : 0.f;
    }
    if (t < 8 && eS[t] >= 0) {
      int e = eS[t];
      float q = 0.f;
#pragma unroll
      for (int k = 0; k < 8; k++) q += edge_feats[e * 8 + k] * Wd[k];
      q *= 0.35355339059327373f;
      denss[t] = tanhf(q * q);
    }
    __syncthreads();
// h1 = silu(ef@W1/4)
#pragma unroll
    for (int rep = 0; rep < 2; rep++) {
      int g = gwave + rep * 4;
      float s = 0.f;
#pragma unroll
      for (int k = 0; k < 16; k++) s += ef[g][k] * W1[k * 64 + o6];
      hA[g][o6] = silu_f(s * 0.25f);
    }
    __syncthreads();
// h2 = silu(h1@W2/8)
#pragma unroll
    for (int rep = 0; rep < 2; rep++) {
      int g = gwave + rep * 4;
      float s = 0.f;
#pragma unroll 8
      for (int k = 0; k < 64; k++) s += hA[g][k] * W2[k * 64 + o6];
      hB[g][o6] = silu_f(s * 0.125f);
    }
    __syncthreads();
// h3 = silu(h2@W3/8)  (write back into hA)
#pragma unroll
    for (int rep = 0; rep < 2; rep++) {
      int g = gwave + rep * 4;
      float s = 0.f;
#pragma unroll 8
      for (int k = 0; k < 64; k++) s += hB[g][k] * W3[k * 64 + o6];
      hA[g][o6] = silu_f(s * 0.125f);
    }
    __syncthreads();
    // w4 = h3@W4/8 : 512 outs/edge, thread handles o=t and o=t+256, all 8 edges
    {
      float a[8] = {0, 0, 0, 0, 0, 0, 0, 0};
      float b[8] = {0, 0, 0, 0, 0, 0, 0, 0};
#pragma unroll 8
      for (int k = 0; k < 64; k++) {
        float w0 = W4[k * 512 + t];
        float w1 = W4[k * 512 + t + 256];
#pragma unroll
        for (int g = 0; g < 8; g++) {
          float h = hA[g][k];
          a[g] += h * w0;
          b[g] += h * w1;
        }
      }
      int p0 = (t & 3) * 128 + (t >> 2);
      int p1 = (t & 3) * 128 + 64 + (t >> 2);
#pragma unroll
      for (int g = 0; g < 8; g++) {
        w4s[g][p0] = a[g] * 0.125f;
        w4s[g][p1] = b[g] * 0.125f;
      }
    }
    // wmm = ef@Mc : 256 outs/edge
    {
      float c[8] = {0, 0, 0, 0, 0, 0, 0, 0};
#pragma unroll
      for (int k = 0; k < 16; k++) {
        float w = Mc[k * 256 + t];
#pragma unroll
        for (int g = 0; g < 8; g++) c[g] += ef[g][k] * w;
      }
      int p = (t & 1) * 128 + (t >> 1);
#pragma unroll
      for (int g = 0; g < 8; g++) wmms[g][p] = c[g];
    }
    __syncthreads();
// ---- TP chain + accumulate (thread owns u, half picks k-range)
#pragma unroll 2
    for (int g = 0; g < 8; g++) {
      float xj = xjs[g][u];
      float sh0 = shs[g][0];
      float w40 = w4s[g][u];
      float w41 = w4s[g][128 + u];
      float w42 = w4s[g][256 + u];
      float w43 = w4s[g][384 + u];
      float pre0 = w40 * xj * sh0;                 // pre_mji l=0 gate
      float wg0 = wmms[g][u] * pre0;
      float wg1 = wmms[g][128 + u] * pre0;
      float mm0 = wg0 * xj * mmshs[g][0];          // magmom_mji l=0
      float m1 = wg1 * xj;
      float bx = mm0 * xj;
      float b0 = w40 * bx, b1 = w41 * bx, b2 = w42 * bx, b3 = w43 * bx;
      if (half == 0) {
        accmm0 += mm0;
        accmm1 += m1 * mmshs[g][1];
        accm[0] += b0 * sh0;
        accm[1] += b1 * shs[g][1];
        accm[2] += b1 * shs[g][2];
        accm[3] += b1 * shs[g][3];
        accm[4] += b2 * shs[g][4];
        accm[5] += b2 * shs[g][5];
        accm[6] += b2 * shs[g][6];
        accm[7] += b2 * shs[g][7];
      } else {
        accmm0 += m1 * mmshs[g][2];
        accmm1 += m1 * mmshs[g][3];
        accm[0] += b2 * shs[g][8];
        accm[1] += b3 * shs[g][9];
        accm[2] += b3 * shs[g][10];
        accm[3] += b3 * shs[g][11];
        accm[4] += b3 * shs[g][12];
        accm[5] += b3 * shs[g][13];
        accm[6] += b3 * shs[g][14];
        accm[7] += b3 * shs[g][15];
      }
    }
    if (t == 0) {
#pragma unroll
      for (int g = 0; g < 8; g++) accd += denss[g];
    }
  }

  // ---- epilogue: per_l_linear + density divide (msg), W_mlin + /20 (mm)
  __syncthreads();
#pragma unroll
  for (int j = 0; j < 8; j++) msg_s[u][half * 8 + j] = accm[j];
  mm_s[u][half * 2 + 0] = accmm0;
  mm_s[u][half * 2 + 1] = accmm1;
  if (t == 0) dsum_s = accd;
  __syncthreads();
  const float dinv = 1.0f / (dsum_s + 1.0f);

  float outl[8] = {0, 0, 0, 0, 0, 0, 0, 0};
  if (half == 0) {
    for (int uu = 0; uu < 128; uu++) {
      float wl0 = Wlin[uu * 128 + u];
      float wl1 = Wlin[16384 + uu * 128 + u];
      float wl2 = Wlin[32768 + uu * 128 + u];
      outl[0] += msg_s[uu][0] * wl0;
      outl[1] += msg_s[uu][1] * wl1;
      outl[2] += msg_s[uu][2] * wl1;
      outl[3] += msg_s[uu][3] * wl1;
      outl[4] += msg_s[uu][4] * wl2;
      outl[5] += msg_s[uu][5] * wl2;
      outl[6] += msg_s[uu][6] * wl2;
      outl[7] += msg_s[uu][7] * wl2;
    }
  } else {
    for (int uu = 0; uu < 128; uu++) {
      float wl2 = Wlin[32768 + uu * 128 + u];
      float wl3 = Wlin[49152 + uu * 128 + u];
      outl[0] += msg_s[uu][8] * wl2;
      outl[1] += msg_s[uu][9] * wl3;
      outl[2] += msg_s[uu][10] * wl3;
      outl[3] += msg_s[uu][11] * wl3;
      outl[4] += msg_s[uu][12] * wl3;
      outl[5] += msg_s[uu][13] * wl3;
      outl[6] += msg_s[uu][14] * wl3;
      outl[7] += msg_s[uu][15] * wl3;
    }
  }
  const float scl = 0.08838834764831845f * dinv;
  float4 v0 = make_float4(outl[0] * scl, outl[1] * scl, outl[2] * scl, outl[3] * scl);
  float4 v1 = make_float4(outl[4] * scl, outl[5] * scl, outl[6] * scl, outl[7] * scl);
  float4* lp = (float4*)(linm + (size_t)n * 2048 + u * 16 + half * 8);
  lp[0] = v0;
  lp[1] = v1;

  float om0 = 0.f, om1 = 0.f;
  if (half == 0) {
    for (int uu = 0; uu < 128; uu++) {
      om0 += mm_s[uu][0] * Wmlin[uu * 128 + u];
      om1 += mm_s[uu][1] * Wmlin[16384 + uu * 128 + u];
    }
  } else {
    for (int uu = 0; uu < 128; uu++) {
      float wm1 = Wmlin[16384 + uu * 128 + u];
      om0 += mm_s[uu][2] * wm1;
      om1 += mm_s[uu][3] * wm1;
    }
  }
  const float sm = 0.08838834764831845f / 20.0f;
  *(float2*)(linmm + (size_t)n * 512 + u * 4 + half * 2) = make_float2(om0 * sm, om1 * sm);
}

// zero out2 blocks l=2,3 (no path -> zero)
__global__ void k_zero2(float* __restrict__ out2, int Nn) {
  int i = blockIdx.x * blockDim.x + threadIdx.x;
  if (i < Nn * 128) {
    float4 z = make_float4(0.f, 0.f, 0.f, 0.f);
    float4* p = (float4*)(out2 + (size_t)i * 16);
    p[1] = z;
    p[2] = z;
    p[3] = z;
  }
}

// ---------------- skip tensor product ----------------
// out[n,v,off+m] = (1/sqrt(1280)) * sum_u in[n,u,m] * (sum_z attrs[n,z]*W[u,z,v])
template <int D>
__device__ __forceinline__ void skip_body(
    const float* __restrict__ attrs, const float* __restrict__ in, int in_rs,
    int in_us, int in_cb, const float* __restrict__ W, float* __restrict__ outp,
    int out_cb, int Nn, int n0, float* lin_s, float (*attrs_s)[10], float* wrow) {
  const int t = threadIdx.x;
  for (int i = t; i < 160; i += 256) {
    int nn = i / 10, z = i - nn * 10;
    int n = n0 + nn;
    attrs_s[nn][z] = (n < Nn) ? attrs[n * 10 + z] : 0.f;
  }
  const int TL = 16 * 128 * D;
  for (int i = t; i < TL; i += 256) {
    int nn = i / (128 * D);
    int r = i - nn * 128 * D;
    int uu = r / D;
    int m = r - uu * D;
    int n = n0 + nn;
    lin_s[i] = (n < Nn) ? in[(size_t)n * in_rs + uu * in_us + in_cb + m] : 0.f;
  }
  __syncthreads();

  const int v = t & 127, hf = t >> 7;
  float ar[8][10];
#pragma unroll
  for (int q = 0; q < 8; q++)
#pragma unroll
    for (int z = 0; z < 10; z++) ar[q][z] = attrs_s[hf * 8 + q][z];

  float acc[8][D];
#pragma unroll
  for (int q = 0; q < 8; q++)
#pragma unroll
    for (int m = 0; m < D; m++) acc[q][m] = 0.f;

  for (int uu = 0; uu < 128; uu++) {
    __syncthreads();
    for (int i = t; i < 1280; i += 256) wrow[i] = W[uu * 1280 + i];
    __syncthreads();
    float wr[10];
#pragma unroll
    for (int z = 0; z < 10; z++) wr[z] = wrow[z * 128 + v];
#pragma unroll
    for (int q = 0; q < 8; q++) {
      int nn = hf * 8 + q;
      float wn = 0.f;
#pragma unroll
      for (int z = 0; z < 10; z++) wn += ar[q][z] * wr[z];
      const float* ls = &lin_s[(nn * 128 + uu) * D];
#pragma unroll
      for (int m = 0; m < D; m++) acc[q][m] += ls[m] * wn;
    }
  }
#pragma unroll
  for (int q = 0; q < 8; q++) {
    int n = n0 + hf * 8 + q;
    if (n < Nn) {
      float* op = outp + (size_t)n * 2048 + v * 16 + out_cb;
#pragma unroll
      for (int m = 0; m < D; m++) op[m] = acc[q][m] * 0.027950849718747371f;
    }
  }
}

__global__ __launch_bounds__(256) void k_skip(
    const float* __restrict__ attrs, const float* __restrict__ linm,
    const float* __restrict__ linmm, const float* __restrict__ Wskip,
    const float* __restrict__ Wmskip, float* __restrict__ out, int Nn) {
  __shared__ float lin_s[16 * 128 * 7];
  __shared__ float attrs_s[16][10];
  __shared__ float wrow[1280];
  const int n0 = blockIdx.x * 16;
  const int job = blockIdx.y;
  switch (job) {
    case 0: skip_body<1>(attrs, linm, 2048, 16, 0, Wskip,              out, 0, Nn, n0, lin_s, attrs_s, wrow); break;
    case 1: skip_body<3>(attrs, linm, 2048, 16, 1, Wskip + 163840,     out, 1, Nn, n0, lin_s, attrs_s, wrow); break;
    case 2: skip_body<5>(attrs, linm, 2048, 16, 4, Wskip + 2 * 163840, out, 4, Nn, n0, lin_s, attrs_s, wrow); break;
    case 3: skip_body<7>(attrs, linm, 2048, 16, 9, Wskip + 3 * 163840, out, 9, Nn, n0, lin_s, attrs_s, wrow); break;
    case 4: skip_body<1>(attrs, linmm, 512, 4, 0, Wmskip,          out + (size_t)Nn * 2048, 0, Nn, n0, lin_s, attrs_s, wrow); break;
    case 5: skip_body<3>(attrs, linmm, 512, 4, 1, Wmskip + 163840, out + (size_t)Nn * 2048, 1, Nn, n0, lin_s, attrs_s, wrow); break;
  }
}

extern "C" void kernel_launch(void* const* d_in, const int* in_sizes, int n_in,
                              void* d_out, int out_size, void* d_ws, size_t ws_size,
                              hipStream_t stream) {
  const float* node_attrs = (const float*)d_in[0];
  const float* node_feats = (const float*)d_in[1];
  const float* edge_attrs = (const float*)d_in[2];
  const float* edge_feats = (const float*)d_in[3];
  const float* mminv = (const float*)d_in[4];
  const float* mmattrs = (const float*)d_in[5];
  const int* edge_index = (const int*)d_in[6];
  const float* W_up = (const float*)d_in[7];
  const float* W1 = (const float*)d_in[8];
  const float* W2 = (const float*)d_in[9];
  const float* W3 = (const float*)d_in[10];
  const float* W4 = (const float*)d_in[11];
  const float* M1 = (const float*)d_in[12];
  const float* M2 = (const float*)d_in[13];
  const float* M3 = (const float*)d_in[14];
  const float* M4 = (const float*)d_in[15];
  const float* Wd = (const float*)d_in[16];
  const float* Wlin = (const float*)d_in[17];
  const float* Wmlin = (const float*)d_in[18];
  const float* Wskip = (const float*)d_in[19];
  const float* Wmskip = (const float*)d_in[20];

  const int N = in_sizes[1] / 128;
  const int E = in_sizes[2] / 16;
  const int* sender = edge_index;
  const int* recv = edge_index + E;

  float* ws = (float*)d_ws;
  float* x = ws;        ws += (size_t)N * 128;
  float* Mc = ws;       ws += 16 * 256;
  float* linm = ws;     ws += (size_t)N * 2048;
  float* linmm = ws;    ws += (size_t)N * 512;
  int* ibuf = (int*)ws;
  int* rowstart = ibuf;            // N+1
  int* deg = ibuf + (N + 1);       // N
  int* cursor = deg + N;           // N
  int* elist = cursor + N;         // E

  k_zero_int<<<(N + 255) / 256, 256, 0, stream>>>(deg, N);
  k_prep<<<1, 256, 0, stream>>>(M1, M2, M3, M4, Mc);
  k_up<<<N, 128, 0, stream>>>(node_feats, W_up, x, N);
  k_count<<<(E + 255) / 256, 256, 0, stream>>>(recv, deg, E);
  k_scan<<<1, 1024, 0, stream>>>(deg, rowstart, cursor, N);
  k_fill<<<(E + 255) / 256, 256, 0, stream>>>(recv, cursor, elist, E);
  k_gather<<<N, 256, 0, stream>>>(x, edge_attrs, edge_feats, mminv, mmattrs,
                                  sender, W1, W2, W3, W4, Mc, Wd, Wlin, Wmlin,
                                  rowstart, elist, linm, linmm, N);
  k_zero2<<<(N * 128 + 255) / 256, 256, 0, stream>>>((float*)d_out + (size_t)N * 2048, N);
  dim3 gs((N + 15) / 16, 6);
  k_skip<<<gs, 256, 0, stream>>>(node_attrs, linm, linmm, Wskip, Wmskip,
                                 (float*)d_out, N);
}

// Round 2
// 1058.889 us; speedup vs baseline: 1.8637x; 1.8637x over previous
//
#include <hip/hip_runtime.h>

// MUL=128, Z=10, L_DIMS=(1,3,5,7) offs (0,1,4,9), MM_DIMS=(1,3)

__device__ __forceinline__ float silu_f(float x) {
  return x / (1.0f + __expf(-x));
}

__global__ void k_zero_int(int* p, int n) {
  int i = blockIdx.x * blockDim.x + threadIdx.x;
  if (i < n) p[i] = 0;
}

// Mc = M1@M2@M3@M4 / 2048  (linear MLP collapse), Mc is [16,256]
__global__ __launch_bounds__(256) void k_prep(
    const float* __restrict__ M1, const float* __restrict__ M2,
    const float* __restrict__ M3, const float* __restrict__ M4,
    float* __restrict__ Mc) {
  __shared__ float T1[16 * 64];
  __shared__ float T2[16 * 64];
  int t = threadIdx.x;
  for (int i = t; i < 16 * 64; i += 256) {
    int r = i >> 6, c = i & 63;
    float s = 0.f;
    for (int k = 0; k < 64; k++) s += M1[r * 64 + k] * M2[k * 64 + c];
    T1[i] = s;
  }
  __syncthreads();
  for (int i = t; i < 16 * 64; i += 256) {
    int r = i >> 6, c = i & 63;
    float s = 0.f;
    for (int k = 0; k < 64; k++) s += T1[r * 64 + k] * M3[k * 64 + c];
    T2[i] = s;
  }
  __syncthreads();
  for (int i = t; i < 16 * 256; i += 256) {
    int r = i >> 8, c = i & 255;
    float s = 0.f;
    for (int k = 0; k < 64; k++) s += T2[r * 64 + k] * M4[k * 256 + c];
    Mc[i] = s * (1.0f / 2048.0f);
  }
}

// x = node_feats @ W_up / sqrt(128)   one block per node, 128 threads
__global__ __launch_bounds__(128) void k_up(const float* __restrict__ nf,
                                            const float* __restrict__ W,
                                            float* __restrict__ x, int Nn) {
  int n = blockIdx.x;
  int v = threadIdx.x;
  __shared__ float row[128];
  row[v] = nf[n * 128 + v];
  __syncthreads();
  float s = 0.f;
#pragma unroll 8
  for (int k = 0; k < 128; k++) s += row[k] * W[k * 128 + v];
  x[n * 128 + v] = s * 0.08838834764831845f;
}

__global__ void k_count(const int* __restrict__ recv, int* __restrict__ deg, int E) {
  int e = blockIdx.x * blockDim.x + threadIdx.x;
  if (e < E) atomicAdd(&deg[recv[e]], 1);
}

// exclusive scan of deg -> rowstart[0..N], cursor copy. single block 1024 threads.
__global__ __launch_bounds__(1024) void k_scan(const int* __restrict__ deg,
                                               int* __restrict__ rowstart,
                                               int* __restrict__ cursor, int Nn) {
  __shared__ int part[1024];
  int t = threadIdx.x;
  int chunk = (Nn + 1023) / 1024;
  int lo = t * chunk;
  int hi = lo + chunk; if (hi > Nn) hi = Nn; if (lo > Nn) lo = Nn;
  int s = 0;
  for (int i = lo; i < hi; i++) s += deg[i];
  part[t] = s;
  __syncthreads();
  for (int o = 1; o < 1024; o <<= 1) {
    int v = (t >= o) ? part[t - o] : 0;
    __syncthreads();
    part[t] += v;
    __syncthreads();
  }
  int base = (t == 0) ? 0 : part[t - 1];
  for (int i = lo; i < hi; i++) {
    rowstart[i] = base;
    cursor[i] = base;
    base += deg[i];
  }
  if (t == 1023) rowstart[Nn] = part[1023];
}

__global__ void k_fill(const int* __restrict__ recv, int* __restrict__ cursor,
                       int* __restrict__ elist, int E) {
  int e = blockIdx.x * blockDim.x + threadIdx.x;
  if (e < E) {
    int p = atomicAdd(&cursor[recv[e]], 1);
    elist[p] = e;
  }
}

// ---------------- main fused per-node kernel ----------------
__global__ __launch_bounds__(256) void k_gather(
    const float* __restrict__ x, const float* __restrict__ edge_attrs,
    const float* __restrict__ edge_feats, const float* __restrict__ mminv,
    const float* __restrict__ mmattrs, const int* __restrict__ sender,
    const float* __restrict__ W1, const float* __restrict__ W2,
    const float* __restrict__ W3, const float* __restrict__ W4,
    const float* __restrict__ Mc, const float* __restrict__ Wd,
    const float* __restrict__ Wlin, const float* __restrict__ Wmlin,
    const int* __restrict__ rowstart, const int* __restrict__ elist,
    float* __restrict__ linm, float* __restrict__ linmm, int Nn) {
  const int n = blockIdx.x;
  const int t = threadIdx.x;
  const int start = rowstart[n], end = rowstart[n + 1];

  __shared__ float ef[8][16];
  __shared__ float hA[8][64];
  __shared__ float hB[8][64];
  __shared__ float w4s[8][512];   // transposed: [l*128+u]
  __shared__ float wmms[8][256];  // transposed: [j*128+u]
  __shared__ float xjs[8][128];
  __shared__ float shs[8][16];
  __shared__ float mmshs[8][4];
  __shared__ float denss[8];
  __shared__ int eS[8], sS[8];
  __shared__ float dsum_s;
  __shared__ float msg_s[128][17];  // +1 pad
  __shared__ float mm_s[128][5];

  float accm[8] = {0, 0, 0, 0, 0, 0, 0, 0};
  float accmm0 = 0.f, accmm1 = 0.f;
  float accd = 0.f;

  const int u = t & 127;
  const int half = t >> 7;  // wave-uniform
  const int gwave = t >> 6;
  const int o6 = t & 63;

  for (int base = start; base < end; base += 8) {
    __syncthreads();
    if (t < 8) {
      int g = t;
      if (base + g < end) {
        int e = elist[base + g];
        eS[g] = e;
        sS[g] = sender[e];
      } else {
        eS[g] = -1;
        sS[g] = 0;
        denss[g] = 0.f;
      }
    }
    __syncthreads();
    if (t < 128) {
      int g = t >> 4, j = t & 15;
      int e = eS[g];
      float v = 0.f, sh = 0.f;
      if (e >= 0) {
        int s = sS[g];
        v = (j < 8) ? edge_feats[e * 8 + j] : mminv[s * 8 + (j - 8)];
        sh = edge_attrs[e * 16 + j];
      }
      ef[g][j] = v;
      shs[g][j] = sh;
    } else if (t < 160) {
      int g = (t - 128) >> 2, j = (t - 128) & 3;
      mmshs[g][j] = (eS[g] >= 0) ? mmattrs[sS[g] * 4 + j] : 0.f;
    }
    for (int i = t; i < 1024; i += 256) {
      int g = i >> 7, uu = i & 127;
      xjs[g][uu] = (eS[g] >= 0) ? x[sS[g] * 128 + uu] : 0.f;
    }
    if (t < 8 && eS[t] >= 0) {
      int e = eS[t];
      float q = 0.f;
#pragma unroll
      for (int k = 0; k < 8; k++) q += edge_feats[e * 8 + k] * Wd[k];
      q *= 0.35355339059327373f;
      denss[t] = tanhf(q * q);
    }
    __syncthreads();
#pragma unroll
    for (int rep = 0; rep < 2; rep++) {
      int g = gwave + rep * 4;
      float s = 0.f;
#pragma unroll
      for (int k = 0; k < 16; k++) s += ef[g][k] * W1[k * 64 + o6];
      hA[g][o6] = silu_f(s * 0.25f);
    }
    __syncthreads();
#pragma unroll
    for (int rep = 0; rep < 2; rep++) {
      int g = gwave + rep * 4;
      float s = 0.f;
#pragma unroll 8
      for (int k = 0; k < 64; k++) s += hA[g][k] * W2[k * 64 + o6];
      hB[g][o6] = silu_f(s * 0.125f);
    }
    __syncthreads();
#pragma unroll
    for (int rep = 0; rep < 2; rep++) {
      int g = gwave + rep * 4;
      float s = 0.f;
#pragma unroll 8
      for (int k = 0; k < 64; k++) s += hB[g][k] * W3[k * 64 + o6];
      hA[g][o6] = silu_f(s * 0.125f);
    }
    __syncthreads();
    {
      float a[8] = {0, 0, 0, 0, 0, 0, 0, 0};
      float b[8] = {0, 0, 0, 0, 0, 0, 0, 0};
#pragma unroll 8
      for (int k = 0; k < 64; k++) {
        float w0 = W4[k * 512 + t];
        float w1 = W4[k * 512 + t + 256];
#pragma unroll
        for (int g = 0; g < 8; g++) {
          float h = hA[g][k];
          a[g] += h * w0;
          b[g] += h * w1;
        }
      }
      int p0 = (t & 3) * 128 + (t >> 2);
      int p1 = (t & 3) * 128 + 64 + (t >> 2);
#pragma unroll
      for (int g = 0; g < 8; g++) {
        w4s[g][p0] = a[g] * 0.125f;
        w4s[g][p1] = b[g] * 0.125f;
      }
    }
    {
      float c[8] = {0, 0, 0, 0, 0, 0, 0, 0};
#pragma unroll
      for (int k = 0; k < 16; k++) {
        float w = Mc[k * 256 + t];
#pragma unroll
        for (int g = 0; g < 8; g++) c[g] += ef[g][k] * w;
      }
      int p = (t & 1) * 128 + (t >> 1);
#pragma unroll
      for (int g = 0; g < 8; g++) wmms[g][p] = c[g];
    }
    __syncthreads();
#pragma unroll 2
    for (int g = 0; g < 8; g++) {
      float xj = xjs[g][u];
      float sh0 = shs[g][0];
      float w40 = w4s[g][u];
      float w41 = w4s[g][128 + u];
      float w42 = w4s[g][256 + u];
      float w43 = w4s[g][384 + u];
      float pre0 = w40 * xj * sh0;
      float wg0 = wmms[g][u] * pre0;
      float wg1 = wmms[g][128 + u] * pre0;
      float mm0 = wg0 * xj * mmshs[g][0];
      float m1 = wg1 * xj;
      float bx = mm0 * xj;
      float b0 = w40 * bx, b1 = w41 * bx, b2 = w42 * bx, b3 = w43 * bx;
      if (half == 0) {
        accmm0 += mm0;
        accmm1 += m1 * mmshs[g][1];
        accm[0] += b0 * sh0;
        accm[1] += b1 * shs[g][1];
        accm[2] += b1 * shs[g][2];
        accm[3] += b1 * shs[g][3];
        accm[4] += b2 * shs[g][4];
        accm[5] += b2 * shs[g][5];
        accm[6] += b2 * shs[g][6];
        accm[7] += b2 * shs[g][7];
      } else {
        accmm0 += m1 * mmshs[g][2];
        accmm1 += m1 * mmshs[g][3];
        accm[0] += b2 * shs[g][8];
        accm[1] += b3 * shs[g][9];
        accm[2] += b3 * shs[g][10];
        accm[3] += b3 * shs[g][11];
        accm[4] += b3 * shs[g][12];
        accm[5] += b3 * shs[g][13];
        accm[6] += b3 * shs[g][14];
        accm[7] += b3 * shs[g][15];
      }
    }
    if (t == 0) {
#pragma unroll
      for (int g = 0; g < 8; g++) accd += denss[g];
    }
  }

  __syncthreads();
#pragma unroll
  for (int j = 0; j < 8; j++) msg_s[u][half * 8 + j] = accm[j];
  mm_s[u][half * 2 + 0] = accmm0;
  mm_s[u][half * 2 + 1] = accmm1;
  if (t == 0) dsum_s = accd;
  __syncthreads();
  const float dinv = 1.0f / (dsum_s + 1.0f);

  float outl[8] = {0, 0, 0, 0, 0, 0, 0, 0};
  if (half == 0) {
    for (int uu = 0; uu < 128; uu++) {
      float wl0 = Wlin[uu * 128 + u];
      float wl1 = Wlin[16384 + uu * 128 + u];
      float wl2 = Wlin[32768 + uu * 128 + u];
      outl[0] += msg_s[uu][0] * wl0;
      outl[1] += msg_s[uu][1] * wl1;
      outl[2] += msg_s[uu][2] * wl1;
      outl[3] += msg_s[uu][3] * wl1;
      outl[4] += msg_s[uu][4] * wl2;
      outl[5] += msg_s[uu][5] * wl2;
      outl[6] += msg_s[uu][6] * wl2;
      outl[7] += msg_s[uu][7] * wl2;
    }
  } else {
    for (int uu = 0; uu < 128; uu++) {
      float wl2 = Wlin[32768 + uu * 128 + u];
      float wl3 = Wlin[49152 + uu * 128 + u];
      outl[0] += msg_s[uu][8] * wl2;
      outl[1] += msg_s[uu][9] * wl3;
      outl[2] += msg_s[uu][10] * wl3;
      outl[3] += msg_s[uu][11] * wl3;
      outl[4] += msg_s[uu][12] * wl3;
      outl[5] += msg_s[uu][13] * wl3;
      outl[6] += msg_s[uu][14] * wl3;
      outl[7] += msg_s[uu][15] * wl3;
    }
  }
  const float scl = 0.08838834764831845f * dinv;
  float4 v0 = make_float4(outl[0] * scl, outl[1] * scl, outl[2] * scl, outl[3] * scl);
  float4 v1 = make_float4(outl[4] * scl, outl[5] * scl, outl[6] * scl, outl[7] * scl);
  float4* lp = (float4*)(linm + (size_t)n * 2048 + u * 16 + half * 8);
  lp[0] = v0;
  lp[1] = v1;

  float om0 = 0.f, om1 = 0.f;
  if (half == 0) {
    for (int uu = 0; uu < 128; uu++) {
      om0 += mm_s[uu][0] * Wmlin[uu * 128 + u];
      om1 += mm_s[uu][1] * Wmlin[16384 + uu * 128 + u];
    }
  } else {
    for (int uu = 0; uu < 128; uu++) {
      float wm1 = Wmlin[16384 + uu * 128 + u];
      om0 += mm_s[uu][2] * wm1;
      om1 += mm_s[uu][3] * wm1;
    }
  }
  const float sm = 0.08838834764831845f / 20.0f;
  *(float2*)(linmm + (size_t)n * 512 + u * 4 + half * 2) = make_float2(om0 * sm, om1 * sm);
}

// zero out2 blocks l=2,3 (no path -> zero)
__global__ void k_zero2(float* __restrict__ out2, int Nn) {
  int i = blockIdx.x * blockDim.x + threadIdx.x;
  if (i < Nn * 128) {
    float4 z = make_float4(0.f, 0.f, 0.f, 0.f);
    float4* p = (float4*)(out2 + (size_t)i * 16);
    p[1] = z;
    p[2] = z;
    p[3] = z;
  }
}

// ---------------- skip tensor product (v2: barrier-free inner loop) ----------
// Pre-transpose W: Wt[L][u][v][12] with z innermost (z=10 used, 2 pad) so each
// thread streams its own W column with b128 loads; no LDS round-trip, no
// per-u barriers.
__global__ __launch_bounds__(128) void k_wt(const float* __restrict__ Wskip,
                                            const float* __restrict__ Wmskip,
                                            float* __restrict__ Wt) {
  int bx = blockIdx.x;              // 0..767 : L = bx>>7, u = bx&127
  int L = bx >> 7, u = bx & 127;
  int v = threadIdx.x;
  const float* src = (L < 4) ? (Wskip + (size_t)L * 163840)
                             : (Wmskip + (size_t)(L - 4) * 163840);
  float* dst = Wt + (((size_t)L * 128 + u) * 128 + v) * 12;
#pragma unroll
  for (int z = 0; z < 10; z++) dst[z] = src[u * 1280 + z * 128 + v];
  dst[10] = 0.f;
  dst[11] = 0.f;
}

// out[n,v,off+m] = (1/sqrt(1280)) * sum_u in[n,u,m] * (sum_z attrs[n,z]*Wt[u,v,z])
template <int D, int SP>
__device__ __forceinline__ void skip_body2(
    const float* __restrict__ attrs, const float* __restrict__ in, int in_rs,
    int in_us, int in_cb, const float* __restrict__ Wt, float* __restrict__ outp,
    int out_cb, int Nn, int n0, float* lin_s, float (*attrs_s)[10]) {
  const int t = threadIdx.x;
  for (int i = t; i < 160; i += 256) {
    int nn = i / 10, z = i - nn * 10;
    int n = n0 + nn;
    attrs_s[nn][z] = (n < Nn) ? attrs[n * 10 + z] : 0.f;
  }
  for (int i = t; i < 16 * 128 * D; i += 256) {
    int nn = i / (128 * D);
    int r = i - nn * 128 * D;
    int uu = r / D;
    int m = r - uu * D;
    int n = n0 + nn;
    lin_s[(nn * 128 + uu) * SP + m] =
        (n < Nn) ? in[(size_t)n * in_rs + uu * in_us + in_cb + m] : 0.f;
  }
  __syncthreads();

  const int v = t & 127, hf = t >> 7;
  float ar[8][10];
#pragma unroll
  for (int q = 0; q < 8; q++)
#pragma unroll
    for (int z = 0; z < 10; z++) ar[q][z] = attrs_s[hf * 8 + q][z];

  float acc[8][D];
#pragma unroll
  for (int q = 0; q < 8; q++)
#pragma unroll
    for (int m = 0; m < D; m++) acc[q][m] = 0.f;

  const float* wp0 = Wt + (size_t)v * 12;
  for (int u = 0; u < 128; u++) {
    const float* wp = wp0 + (size_t)u * 1536;  // 128*12
    float4 wa = *(const float4*)wp;
    float4 wb = *(const float4*)(wp + 4);
    float2 wc = *(const float2*)(wp + 8);
    float wr[10] = {wa.x, wa.y, wa.z, wa.w, wb.x, wb.y, wb.z, wb.w, wc.x, wc.y};
#pragma unroll
    for (int q = 0; q < 8; q++) {
      float wn = 0.f;
#pragma unroll
      for (int z = 0; z < 10; z++) wn += ar[q][z] * wr[z];
      const float* ls = &lin_s[((hf * 8 + q) * 128 + u) * SP];
#pragma unroll
      for (int m = 0; m < D; m++) acc[q][m] += ls[m] * wn;
    }
  }
#pragma unroll
  for (int q = 0; q < 8; q++) {
    int n = n0 + hf * 8 + q;
    if (n < Nn) {
      float* op = outp + (size_t)n * 2048 + v * 16 + out_cb;
#pragma unroll
      for (int m = 0; m < D; m++) op[m] = acc[q][m] * 0.027950849718747371f;
    }
  }
}

__global__ __launch_bounds__(256) void k_skip(
    const float* __restrict__ attrs, const float* __restrict__ linm,
    const float* __restrict__ linmm, const float* __restrict__ Wt,
    float* __restrict__ out, int Nn) {
  __shared__ float lin_s[16 * 128 * 8];
  __shared__ float attrs_s[16][10];
  const int n0 = blockIdx.x * 16;
  const int job = blockIdx.y;
  const float* Wtj = Wt + (size_t)job * 128 * 128 * 12;
  switch (job) {
    case 0: skip_body2<1, 1>(attrs, linm, 2048, 16, 0, Wtj, out, 0, Nn, n0, lin_s, attrs_s); break;
    case 1: skip_body2<3, 4>(attrs, linm, 2048, 16, 1, Wtj, out, 1, Nn, n0, lin_s, attrs_s); break;
    case 2: skip_body2<5, 8>(attrs, linm, 2048, 16, 4, Wtj, out, 4, Nn, n0, lin_s, attrs_s); break;
    case 3: skip_body2<7, 8>(attrs, linm, 2048, 16, 9, Wtj, out, 9, Nn, n0, lin_s, attrs_s); break;
    case 4: skip_body2<1, 1>(attrs, linmm, 512, 4, 0, Wtj, out + (size_t)Nn * 2048, 0, Nn, n0, lin_s, attrs_s); break;
    case 5: skip_body2<3, 4>(attrs, linmm, 512, 4, 1, Wtj, out + (size_t)Nn * 2048, 1, Nn, n0, lin_s, attrs_s); break;
  }
}

extern "C" void kernel_launch(void* const* d_in, const int* in_sizes, int n_in,
                              void* d_out, int out_size, void* d_ws, size_t ws_size,
                              hipStream_t stream) {
  const float* node_attrs = (const float*)d_in[0];
  const float* node_feats = (const float*)d_in[1];
  const float* edge_attrs = (const float*)d_in[2];
  const float* edge_feats = (const float*)d_in[3];
  const float* mminv = (const float*)d_in[4];
  const float* mmattrs = (const float*)d_in[5];
  const int* edge_index = (const int*)d_in[6];
  const float* W_up = (const float*)d_in[7];
  const float* W1 = (const float*)d_in[8];
  const float* W2 = (const float*)d_in[9];
  const float* W3 = (const float*)d_in[10];
  const float* W4 = (const float*)d_in[11];
  const float* M1 = (const float*)d_in[12];
  const float* M2 = (const float*)d_in[13];
  const float* M3 = (const float*)d_in[14];
  const float* M4 = (const float*)d_in[15];
  const float* Wd = (const float*)d_in[16];
  const float* Wlin = (const float*)d_in[17];
  const float* Wmlin = (const float*)d_in[18];
  const float* Wskip = (const float*)d_in[19];
  const float* Wmskip = (const float*)d_in[20];

  const int N = in_sizes[1] / 128;
  const int E = in_sizes[2] / 16;
  const int* sender = edge_index;
  const int* recv = edge_index + E;

  float* ws = (float*)d_ws;
  float* x = ws;        ws += (size_t)N * 128;
  float* Mc = ws;       ws += 16 * 256;
  float* linm = ws;     ws += (size_t)N * 2048;
  float* linmm = ws;    ws += (size_t)N * 512;
  float* Wt = ws;       ws += (size_t)6 * 128 * 128 * 12;
  int* ibuf = (int*)ws;
  int* rowstart = ibuf;            // N+1
  int* deg = ibuf + (N + 1);       // N
  int* cursor = deg + N;           // N
  int* elist = cursor + N;         // E

  k_zero_int<<<(N + 255) / 256, 256, 0, stream>>>(deg, N);
  k_prep<<<1, 256, 0, stream>>>(M1, M2, M3, M4, Mc);
  k_wt<<<768, 128, 0, stream>>>(Wskip, Wmskip, Wt);
  k_up<<<N, 128, 0, stream>>>(node_feats, W_up, x, N);
  k_count<<<(E + 255) / 256, 256, 0, stream>>>(recv, deg, E);
  k_scan<<<1, 1024, 0, stream>>>(deg, rowstart, cursor, N);
  k_fill<<<(E + 255) / 256, 256, 0, stream>>>(recv, cursor, elist, E);
  k_gather<<<N, 256, 0, stream>>>(x, edge_attrs, edge_feats, mminv, mmattrs,
                                  sender, W1, W2, W3, W4, Mc, Wd, Wlin, Wmlin,
                                  rowstart, elist, linm, linmm, N);
  k_zero2<<<(N * 128 + 255) / 256, 256, 0, stream>>>((float*)d_out + (size_t)N * 2048, N);
  dim3 gs((N + 15) / 16, 6);
  k_skip<<<gs, 256, 0, stream>>>(node_attrs, linm, linmm, Wt, (float*)d_out, N);
}